// Round 2
// 1240.534 us; speedup vs baseline: 1.0310x; 1.0310x over previous
//
#include <hip/hip_runtime.h>

// ConvGRU, fp16 MFMA implicit GEMM, PER-LAYER FUSED cells (gates+cand+update
// in one kernel; 2 dispatches/timestep instead of 4).
//   - gates computed on 6x34 halo region (204px, 13 M-tiles/WG) so r*h is
//     available in LDS with the 1-px halo the candidate conv needs
//   - RH / zbuf global round-trips eliminated (LDS-resident rh[6x34], z[4x32])
//   - h_old for the update read from the staged LDS tile, not global
//   - states ping-pong double-buffered (S0A/S0B, S1A/S1B): fused kernel reads
//     the state plane WITH HALO and writes it -> same-dispatch cross-WG race
//     without double buffering
// States fp16 NHWC padded planes [B][130][130][32], 1-px zero halo. Staged
// tile = 8 rows x 36 cols (2-px halo), DMA via global_load_lds; out-of-plane
// stage rows/cols clamp into the zero halo ring == conv SAME pad value.
// Tile 4 rows x 32 cols out per WG (4 waves), grid 1024.
//
// R1 fix: x staging was missing the per-batch offset (seq is [B,T,H,W]) --
// batch b frame t is at seq + (b*TT + t)*HW. xbs parameter restored.

#define HH 128
#define PH 130
#define HW 16384
#define BB 8
#define TT 16

typedef _Float16 f16x8 __attribute__((ext_vector_type(8)));
typedef float f32x4 __attribute__((ext_vector_type(4)));
typedef unsigned int u32x4 __attribute__((ext_vector_type(4)));

__device__ __forceinline__ unsigned short f2h(float x){
    return __builtin_bit_cast(unsigned short, (_Float16)x);
}
__device__ __forceinline__ float h2f(unsigned short u){
    return (float)__builtin_bit_cast(_Float16, u);
}
__device__ __forceinline__ f16x8 ld_frag(const unsigned short* p){
    u32x4 v = *(const u32x4*)p;
    return __builtin_bit_cast(f16x8, v);
}
// generic LDS fragment read: linear pixel index spix (layout [pix][32ch]), ch octet q
__device__ __forceinline__ f16x8 lds_frag_w(const unsigned short* base, int spix, int q){
    u32x4 v = *(const u32x4*)(base + spix * 32 + q * 8);
    return __builtin_bit_cast(f16x8, v);
}
__device__ __forceinline__ float sigmoid_f(float a){ return 1.0f / (1.0f + __expf(-a)); }
__device__ __forceinline__ float tanh_f(float a){ float e2 = __expf(2.0f * a); return 1.0f - 2.0f / (e2 + 1.0f); }

// ---- async DMA staging: 8x36 pixel tile (288 px * 4 chunks = 18 wave-iters) ----
// stage origin (prow0, pcol0) in PADDED coords; clamped rows/cols land in the
// zero halo ring (pr/pc 0 or 129) == exactly the value SAME-padding requires.
__device__ __forceinline__ void stage_plane(unsigned short* slot,
    const unsigned short* __restrict__ g, int b, int prow0, int pcol0)
{
    const int wv = threadIdx.x >> 6, lane = threadIdx.x & 63;
    for (int k = wv; k < 18; k += 4) {
        int chunk = k * 64 + lane;
        int pix = chunk >> 2, part = chunk & 3;
        int r = pix / 36, c = pix - r * 36;
        int pr = prow0 + r; pr = pr < 0 ? 0 : (pr > 129 ? 129 : pr);
        int pc = pcol0 + c; pc = pc < 0 ? 0 : (pc > 129 ? 129 : pc);
        const unsigned short* ga = g + ((long)((b * PH + pr) * PH + pc) * 32 + part * 8);
        __builtin_amdgcn_global_load_lds(
            (const __attribute__((address_space(1))) unsigned int*)ga,
            (__attribute__((address_space(3))) unsigned int*)(slot + k * 512),
            16, 0, 0);
    }
}

// stage raw x (unpadded fp32 image) 8x36 tile, bounds-checked, stride 37
__device__ __forceinline__ void stage_x(float* xt, const float* __restrict__ x,
                                        int irow0, int icol0)
{
    for (int p = threadIdx.x; p < 288; p += 256) {
        int r = p / 36, c = p - r * 36;
        int ir = irow0 + r, ic = icol0 + c;
        float v = 0.0f;
        if (ir >= 0 && ir < HH && ic >= 0 && ic < HH) v = x[ir * HH + ic];
        xt[r * 37 + c] = v;
    }
}

// ---- weight prep: [cout][cin_tot][9] fp32 -> [step][cout][32] fp16 (unchanged) ----
__global__ void prep_w(const float* __restrict__ w, unsigned short* __restrict__ wf,
                       int CO, int CIT, int NSTEP, int xmode)
{
    int idx = blockIdx.x * 256 + threadIdx.x;
    int total = NSTEP * CO * 32;
    if (idx >= total) return;
    int kk = idx & 31;
    int t  = idx >> 5;
    int co = t % CO;
    int s  = t / CO;
    float v = 0.0f;
    if (xmode && s == NSTEP - 1) {
        if (kk < 9) v = w[(co * CIT + 0) * 9 + kk];
    } else {
        int tap = s % 9;
        int cin = (s / 9) * 32 + kk + (xmode ? 1 : 0);
        v = w[(co * CIT + cin) * 9 + tap];
    }
    wf[idx] = f2h(v);
}

// ---- fused GRU cell. L=0: h0' = cell(x, h0); L=1: h1' = cell(h0', h1) ----
// Hin = old h plane (read), Hout = new h plane (write), Xin = L1's "x" = h0'.
template<int L>
__global__ __launch_bounds__(256, 3)
void cell_fused(const unsigned short* __restrict__ Hin,
                unsigned short* __restrict__ Hout,
                const unsigned short* __restrict__ Xin,
                const float* __restrict__ xraw, long xbs,
                const unsigned short* __restrict__ Wg, const float* __restrict__ bg,
                const unsigned short* __restrict__ Wc, const float* __restrict__ bc)
{
    constexpr int NSLOT = (L == 0) ? 1 : 2;
    constexpr int KG = (L == 0) ? 10 : 18;    // gates k-steps
    constexpr int KC = (L == 0) ? 10 : 18;    // cand  k-steps

    __shared__ __align__(16) unsigned short hsbuf[NSLOT][9216]; // 8x36x32 fp16 plane(s)
    __shared__ __align__(16) unsigned short rh[6528];           // 6x34x32 fp16
    __shared__ __align__(16) unsigned short zt[4096];           // 4x32x32 fp16
    __shared__ float xt[(L == 0) ? 296 : 1];                    // 8x(36+pad) fp32

    unsigned short* hs0 = hsbuf[0];
    unsigned short* hs1 = hsbuf[NSLOT - 1];

    const int b  = blockIdx.y;
    const int tc = blockIdx.x & 3;      // 0..3   (32-col tiles)
    const int tr = blockIdx.x >> 2;     // 0..31  (4-row tiles)
    const int R0 = tr * 4, C0 = tc * 32;           // image coords of out tile
    const int prow0 = R0 - 1, pcol0 = C0 - 1;      // padded coords of stage origin

    // phase 0: staging (gates "x-part" plane -> hs0, gates "h-part" -> hs1/hs0)
    if (L == 0) {
        stage_plane(hs0, Hin, b, prow0, pcol0);            // h0_old
        stage_x(xt, xraw + (long)b * xbs, R0 - 2, C0 - 2); // per-batch frame!
    } else {
        stage_plane(hs0, Xin, b, prow0, pcol0);            // h0_new (x-part)
        stage_plane(hs1, Hin, b, prow0, pcol0);            // h1_old (h-part)
    }
    __syncthreads();   // drains vmcnt(0): DMA complete

    const int wv = threadIdx.x >> 6, lane = threadIdx.x & 63;
    const int m16 = lane & 15, q = lane >> 4;
    const unsigned short* hp = (L == 0) ? hs0 : hs1;       // old-h plane

    // ---- phase 1: gates conv on 6x34 region (204 px -> 13 M-tiles, waves get {4,3,3,3}) ----
    int gr0[4], gc0[4];
#pragma unroll
    for (int i = 0; i < 4; ++i) {
        int p = (wv + i * 4) * 16 + m16; if (p > 203) p = 203;
        gr0[i] = p / 34; gc0[i] = p - gr0[i] * 34;
    }
    f32x4 gacc[4][4];
#pragma unroll
    for (int i = 0; i < 4; ++i) {
        if (wv + i * 4 >= 13) continue;
#pragma unroll
        for (int ng = 0; ng < 4; ++ng) {
            float bv = bg[ng * 16 + m16];
            gacc[i][ng] = f32x4{bv, bv, bv, bv};
        }
    }
#pragma unroll
    for (int s = 0; s < KG; ++s) {
        f16x8 Bf[4];
#pragma unroll
        for (int ng = 0; ng < 4; ++ng)
            Bf[ng] = ld_frag(Wg + (s * 64 + ng * 16 + m16) * 32 + q * 8);
#pragma unroll
        for (int i = 0; i < 4; ++i) {
            if (wv + i * 4 >= 13) continue;
            f16x8 A;
            if (L == 0 && s == 9) {                 // im2col x step
                f16x8 v;
#pragma unroll
                for (int j = 0; j < 8; ++j) {
                    int k = q * 8 + j;
                    float f = 0.0f;
                    if (k < 9) f = xt[(gr0[i] + k / 3) * 37 + gc0[i] + k % 3];
                    v[j] = (_Float16)f;
                }
                A = v;
            } else {
                const int tap = (L == 0) ? s : (s % 9);
                const unsigned short* pl = (L == 1 && s >= 9) ? hs1 : hs0;
                A = lds_frag_w(pl, (gr0[i] + tap / 3) * 36 + gc0[i] + tap % 3, q);
            }
#pragma unroll
            for (int ng = 0; ng < 4; ++ng)
                gacc[i][ng] = __builtin_amdgcn_mfma_f32_16x16x32_f16(A, Bf[ng], gacc[i][ng], 0, 0, 0);
        }
    }
    // gates epilogue: r*h -> rh LDS (all 204 px), z -> zt LDS (interior 4x32).
    // C layout: col(n)=lane&15, row(pixel)=q*4+rg. Clamped pad pixels (204-207)
    // duplicate pixel 203 with bit-identical values -> benign same-value race.
#pragma unroll
    for (int i = 0; i < 4; ++i) {
        if (wv + i * 4 >= 13) continue;
#pragma unroll
        for (int rg = 0; rg < 4; ++rg) {
            int p = (wv + i * 4) * 16 + q * 4 + rg; if (p > 203) p = 203;
            int gr = p / 34, gc = p - (p / 34) * 34;
#pragma unroll
            for (int ng = 0; ng < 2; ++ng) {
                int n = ng * 16 + m16;              // r couts 0-31 = ng 0,1; z = ng 2,3
                float rv = sigmoid_f(gacc[i][ng][rg]);
                float zv = sigmoid_f(gacc[i][ng + 2][rg]);
                float hv = h2f(hp[((gr + 1) * 36 + gc + 1) * 32 + n]);
                rh[(gr * 34 + gc) * 32 + n] = f2h(rv * hv);
                if (gr >= 1 && gr <= 4 && gc >= 1 && gc <= 32)
                    zt[((gr - 1) * 32 + gc - 1) * 32 + n] = f2h(zv);
            }
        }
    }
    __syncthreads();

    // ---- phase 2: candidate conv on interior 4x32 (wave = 1 row, 2 m-tiles) ----
    f32x4 cacc[2][2];
#pragma unroll
    for (int mg = 0; mg < 2; ++mg)
#pragma unroll
        for (int ng = 0; ng < 2; ++ng) {
            float bv = bc[ng * 16 + m16];
            cacc[mg][ng] = f32x4{bv, bv, bv, bv};
        }
#pragma unroll
    for (int s = 0; s < KC; ++s) {
        f16x8 Bf[2];
#pragma unroll
        for (int ng = 0; ng < 2; ++ng)
            Bf[ng] = ld_frag(Wc + (s * 32 + ng * 16 + m16) * 32 + q * 8);
        f16x8 A2[2];
        if (L == 0 && s == 9) {                     // im2col x step
#pragma unroll
            for (int mg = 0; mg < 2; ++mg) {
                f16x8 v;
#pragma unroll
                for (int j = 0; j < 8; ++j) {
                    int k = q * 8 + j;
                    float f = 0.0f;
                    if (k < 9) f = xt[(wv + 1 + k / 3) * 37 + mg * 16 + m16 + 1 + k % 3];
                    v[j] = (_Float16)f;
                }
                A2[mg] = v;
            }
        } else if (L == 1 && s < 9) {               // h0' taps from staged plane
#pragma unroll
            for (int mg = 0; mg < 2; ++mg)
                A2[mg] = lds_frag_w(hs0, (wv + 1 + s / 3) * 36 + mg * 16 + m16 + 1 + s % 3, q);
        } else {                                    // r*h taps from rh buffer
            const int tap = (L == 0) ? s : (s - 9);
#pragma unroll
            for (int mg = 0; mg < 2; ++mg)
                A2[mg] = lds_frag_w(rh, (wv + tap / 3) * 34 + mg * 16 + m16 + tap % 3, q);
        }
#pragma unroll
        for (int mg = 0; mg < 2; ++mg)
#pragma unroll
            for (int ng = 0; ng < 2; ++ng)
                cacc[mg][ng] = __builtin_amdgcn_mfma_f32_16x16x32_f16(A2[mg], Bf[ng], cacc[mg][ng], 0, 0, 0);
    }
    // update epilogue: h' = (1-z)*h_old + z*tanh(n); h_old from staged LDS.
#pragma unroll
    for (int mg = 0; mg < 2; ++mg)
#pragma unroll
        for (int ng = 0; ng < 2; ++ng)
#pragma unroll
            for (int rg = 0; rg < 4; ++rg) {
                int lcol = mg * 16 + q * 4 + rg;
                int n = ng * 16 + m16;
                float nv = tanh_f(cacc[mg][ng][rg]);
                float zz = h2f(zt[(wv * 32 + lcol) * 32 + n]);
                float ho = h2f(hp[((wv + 2) * 36 + lcol + 2) * 32 + n]);
                long psp = (long)(b * PH + R0 + wv + 1) * PH + (C0 + lcol + 1);
                Hout[psp * 32 + n] = f2h((1.0f - zz) * ho + zz * nv);
            }
}

// ---- final: last h1 plane -> d_out NCHW fp32 ----
__global__ void final_out(const unsigned short* __restrict__ S1, float* __restrict__ out)
{
    int i = blockIdx.x * 256 + threadIdx.x;    // B*32*HW = 4194304
    if (i >= BB * 32 * HW) return;
    int pix = i & 16383;
    int t = i >> 14;
    int c = t & 31, b = t >> 5;
    int r = pix >> 7, cc = pix & 127;
    long ps = (long)(b * PH + r + 1) * PH + cc + 1;
    out[i] = h2f(S1[ps * 32 + c]);
}

extern "C" void kernel_launch(void* const* d_in, const int* in_sizes, int n_in,
                              void* d_out, int out_size, void* d_ws, size_t ws_size,
                              hipStream_t stream)
{
    const float* seq = (const float*)d_in[0];
    const float* gw0 = (const float*)d_in[1];
    const float* gb0 = (const float*)d_in[2];
    const float* cw0 = (const float*)d_in[3];
    const float* cb0 = (const float*)d_in[4];
    const float* gw1 = (const float*)d_in[5];
    const float* gb1 = (const float*)d_in[6];
    const float* cw1 = (const float*)d_in[7];
    const float* cb1 = (const float*)d_in[8];
    float* out = (float*)d_out;

    const size_t NSP = (size_t)BB * PH * PH * 32;    // 4,326,400 fp16 per plane

    char* p = (char*)d_ws;
    unsigned short* S0A = (unsigned short*)p; p += NSP * 2;
    unsigned short* S0B = (unsigned short*)p; p += NSP * 2;
    unsigned short* S1A = (unsigned short*)p; p += NSP * 2;
    unsigned short* S1B = (unsigned short*)p; p += NSP * 2;
    unsigned short* WG0 = (unsigned short*)p; p += 20480 * 2;
    unsigned short* WC0 = (unsigned short*)p; p += 10240 * 2;
    unsigned short* WG1 = (unsigned short*)p; p += 36864 * 2;
    unsigned short* WC1 = (unsigned short*)p; p += 18432 * 2;

    // zero all 4 state planes (h=0 init + permanent zero halos), one span
    hipMemsetAsync(S0A, 0, 4 * NSP * 2, stream);

    prep_w<<<(10 * 64 * 32 + 255) / 256, 256, 0, stream>>>(gw0, WG0, 64, 33, 10, 1);
    prep_w<<<(10 * 32 * 32 + 255) / 256, 256, 0, stream>>>(cw0, WC0, 32, 33, 10, 1);
    prep_w<<<(18 * 64 * 32 + 255) / 256, 256, 0, stream>>>(gw1, WG1, 64, 64, 18, 0);
    prep_w<<<(18 * 32 * 32 + 255) / 256, 256, 0, stream>>>(cw1, WC1, 32, 64, 18, 0);

    dim3 grid(128, BB), block(256);
    const long xbs = (long)TT * HW;
    unsigned short *s0r = S0A, *s0w = S0B, *s1r = S1A, *s1w = S1B;
    for (int t = 0; t < TT; ++t) {
        const float* xt = seq + (long)t * HW;
        cell_fused<0><<<grid, block, 0, stream>>>(s0r, s0w, (const unsigned short*)0,
                                                  xt, xbs, WG0, gb0, WC0, cb0);
        cell_fused<1><<<grid, block, 0, stream>>>(s1r, s1w, s0w,
                                                  (const float*)0, xbs, WG1, gb1, WC1, cb1);
        unsigned short* tmp;
        tmp = s0r; s0r = s0w; s0w = tmp;
        tmp = s1r; s1r = s1w; s1w = tmp;
    }
    final_out<<<(BB * 32 * HW + 255) / 256, 256, 0, stream>>>(s1r, out);
}

// Round 3
// 1189.350 us; speedup vs baseline: 1.0754x; 1.0430x over previous
//
#include <hip/hip_runtime.h>

// ConvGRU, fp16 MFMA implicit GEMM, PER-LAYER FUSED cells.
// R2 changes (counter-driven: Occ 19%, 2.57M LDS conflicts, 15% MfmaUtil):
//   - gates pixel enumeration = 8 interior M-tiles ALIGNED with cand-conv
//     fragment layout + 5 halo tiles. Thread that computes gate-z(pixel,ch)
//     is the thread that needs it in the update epilogue -> z kept in
//     REGISTERS (packed f16x2). zt LDS buffer (8.2KB) + its scalar LDS
//     traffic deleted.
//   - halo tiles compute only the r-gate couts (z of halo pixels is dead):
//     gate MFMAs 936->756/WG, wave critical path 288->216.
//   - LDS: L1 58.4->49.9KB (3 WG/CU), L0 40.9->32.7KB (4 WG/CU).
// States fp16 NHWC padded planes [B][130][130][32], 1-px zero halo, ping-pong
// double buffered. Staged tile = 8x36 (2-px halo) via global_load_lds;
// clamped stage rows/cols land in the zero halo ring == SAME-pad value.
// Tile 4 rows x 32 cols out per WG (4 waves), grid 1024.

#define HH 128
#define PH 130
#define HW 16384
#define BB 8
#define TT 16

typedef _Float16 f16x8 __attribute__((ext_vector_type(8)));
typedef float f32x4 __attribute__((ext_vector_type(4)));
typedef unsigned int u32x4 __attribute__((ext_vector_type(4)));

__device__ __forceinline__ unsigned short f2h(float x){
    return __builtin_bit_cast(unsigned short, (_Float16)x);
}
__device__ __forceinline__ float h2f(unsigned short u){
    return (float)__builtin_bit_cast(_Float16, u);
}
__device__ __forceinline__ f16x8 ld_frag(const unsigned short* p){
    u32x4 v = *(const u32x4*)p;
    return __builtin_bit_cast(f16x8, v);
}
__device__ __forceinline__ f16x8 lds_frag_w(const unsigned short* base, int spix, int q){
    u32x4 v = *(const u32x4*)(base + spix * 32 + q * 8);
    return __builtin_bit_cast(f16x8, v);
}
__device__ __forceinline__ float sigmoid_f(float a){ return 1.0f / (1.0f + __expf(-a)); }
__device__ __forceinline__ float tanh_f(float a){ float e2 = __expf(2.0f * a); return 1.0f - 2.0f / (e2 + 1.0f); }

// halo pixel enumeration: 76 px (rows 0,5 full; rows 1-4 cols 0,33) as 5
// 16-px M-tiles; s>75 clamps to 75 (dup rows in fragment -> benign same-value
// dup rh writes, all within one wave).
__device__ __forceinline__ void halo_rc(int s, int& gr, int& gc){
    s = s > 75 ? 75 : s;
    if (s < 34)      { gr = 0;            gc = s;      }
    else if (s < 68) { gr = 5;            gc = s - 34; }
    else if (s < 72) { gr = 1 + (s - 68); gc = 0;      }
    else             { gr = 1 + (s - 72); gc = 33;     }
}

// im2col x fragment for gates pixel (gr,gc) in 6x34 gates coords
__device__ __forceinline__ f16x8 x_im2col(const float* xt, int gr, int gc, int q){
    f16x8 v;
#pragma unroll
    for (int j = 0; j < 8; ++j) {
        int k = q * 8 + j;
        float f = 0.0f;
        if (k < 9) f = xt[(gr + k / 3) * 37 + gc + k % 3];
        v[j] = (_Float16)f;
    }
    return v;
}

// ---- async DMA staging: 8x36 pixel tile (288 px * 4 chunks = 18 wave-iters) ----
__device__ __forceinline__ void stage_plane(unsigned short* slot,
    const unsigned short* __restrict__ g, int b, int prow0, int pcol0)
{
    const int wv = threadIdx.x >> 6, lane = threadIdx.x & 63;
    for (int k = wv; k < 18; k += 4) {
        int chunk = k * 64 + lane;
        int pix = chunk >> 2, part = chunk & 3;
        int r = pix / 36, c = pix - r * 36;
        int pr = prow0 + r; pr = pr < 0 ? 0 : (pr > 129 ? 129 : pr);
        int pc = pcol0 + c; pc = pc < 0 ? 0 : (pc > 129 ? 129 : pc);
        const unsigned short* ga = g + ((long)((b * PH + pr) * PH + pc) * 32 + part * 8);
        __builtin_amdgcn_global_load_lds(
            (const __attribute__((address_space(1))) unsigned int*)ga,
            (__attribute__((address_space(3))) unsigned int*)(slot + k * 512),
            16, 0, 0);
    }
}

// stage raw x (unpadded fp32 image) 8x36 tile, bounds-checked, stride 37
__device__ __forceinline__ void stage_x(float* xt, const float* __restrict__ x,
                                        int irow0, int icol0)
{
    for (int p = threadIdx.x; p < 288; p += 256) {
        int r = p / 36, c = p - r * 36;
        int ir = irow0 + r, ic = icol0 + c;
        float v = 0.0f;
        if (ir >= 0 && ir < HH && ic >= 0 && ic < HH) v = x[ir * HH + ic];
        xt[r * 37 + c] = v;
    }
}

// ---- weight prep: [cout][cin_tot][9] fp32 -> [step][cout][32] fp16 ----
__global__ void prep_w(const float* __restrict__ w, unsigned short* __restrict__ wf,
                       int CO, int CIT, int NSTEP, int xmode)
{
    int idx = blockIdx.x * 256 + threadIdx.x;
    int total = NSTEP * CO * 32;
    if (idx >= total) return;
    int kk = idx & 31;
    int t  = idx >> 5;
    int co = t % CO;
    int s  = t / CO;
    float v = 0.0f;
    if (xmode && s == NSTEP - 1) {
        if (kk < 9) v = w[(co * CIT + 0) * 9 + kk];
    } else {
        int tap = s % 9;
        int cin = (s / 9) * 32 + kk + (xmode ? 1 : 0);
        v = w[(co * CIT + cin) * 9 + tap];
    }
    wf[idx] = f2h(v);
}

// ---- fused GRU cell. L=0: h0' = cell(x, h0); L=1: h1' = cell(h0', h1) ----
template<int L>
__global__ __launch_bounds__(256, (L == 0) ? 4 : 3)
void cell_fused(const unsigned short* __restrict__ Hin,
                unsigned short* __restrict__ Hout,
                const unsigned short* __restrict__ Xin,
                const float* __restrict__ xraw, long xbs,
                const unsigned short* __restrict__ Wg, const float* __restrict__ bg,
                const unsigned short* __restrict__ Wc, const float* __restrict__ bc)
{
    constexpr int NSLOT = (L == 0) ? 1 : 2;
    constexpr int KG = (L == 0) ? 10 : 18;
    constexpr int KC = (L == 0) ? 10 : 18;

    __shared__ __align__(16) unsigned short hsbuf[NSLOT][9216]; // 8x36x32 fp16 plane(s)
    __shared__ __align__(16) unsigned short rh[6528];           // 6x34x32 fp16
    __shared__ float xt[(L == 0) ? 296 : 1];                    // 8x37 fp32

    unsigned short* hs0 = hsbuf[0];
    unsigned short* hs1 = hsbuf[NSLOT - 1];

    const int b  = blockIdx.y;
    const int tc = blockIdx.x & 3;
    const int tr = blockIdx.x >> 2;
    const int R0 = tr * 4, C0 = tc * 32;
    const int prow0 = R0 - 1, pcol0 = C0 - 1;

    if (L == 0) {
        stage_plane(hs0, Hin, b, prow0, pcol0);
        stage_x(xt, xraw + (long)b * xbs, R0 - 2, C0 - 2);
    } else {
        stage_plane(hs0, Xin, b, prow0, pcol0);
        stage_plane(hs1, Hin, b, prow0, pcol0);
    }
    __syncthreads();   // drains vmcnt(0): DMA complete

    const int wv = threadIdx.x >> 6, lane = threadIdx.x & 63;
    const int m16 = lane & 15, q = lane >> 4;
    const unsigned short* hp = (L == 0) ? hs0 : hs1;       // old-h plane

    // ---- phase 1: gates conv ----
    // interior tiles (2/wave): tile (wv, mg) = gates pixels (gr=wv+1, gc=mg*16+1+m)
    // halo tiles: wave wv -> tile wv; wave 0 also tile 4. Halo computes r only.
    int hr0, hc0, hr1, hc1;
    halo_rc(wv * 16 + m16, hr0, hc0);
    halo_rc(64 + m16, hr1, hc1);
    const bool HAS2 = (wv == 0);

    f32x4 gI[2][4];
    f32x4 gH[2][2];
#pragma unroll
    for (int ng = 0; ng < 4; ++ng) {
        float bv = bg[ng * 16 + m16];
#pragma unroll
        for (int mg = 0; mg < 2; ++mg) gI[mg][ng] = f32x4{bv, bv, bv, bv};
        if (ng < 2) { gH[0][ng] = f32x4{bv, bv, bv, bv}; gH[1][ng] = f32x4{bv, bv, bv, bv}; }
    }

#pragma unroll
    for (int s = 0; s < KG; ++s) {
        f16x8 Bf[4];
#pragma unroll
        for (int ng = 0; ng < 4; ++ng)
            Bf[ng] = ld_frag(Wg + (s * 64 + ng * 16 + m16) * 32 + q * 8);
        f16x8 AI[2], AH0, AH1;
        if (L == 0 && s == 9) {
#pragma unroll
            for (int mg = 0; mg < 2; ++mg)
                AI[mg] = x_im2col(xt, wv + 1, mg * 16 + 1 + m16, q);
            AH0 = x_im2col(xt, hr0, hc0, q);
            if (HAS2) AH1 = x_im2col(xt, hr1, hc1, q);
        } else {
            const int tap = (L == 0) ? s : (s % 9);
            const unsigned short* pl = (L == 1 && s >= 9) ? hs1 : hs0;
#pragma unroll
            for (int mg = 0; mg < 2; ++mg)
                AI[mg] = lds_frag_w(pl, (wv + 1 + tap / 3) * 36 + mg * 16 + 1 + m16 + tap % 3, q);
            AH0 = lds_frag_w(pl, (hr0 + tap / 3) * 36 + hc0 + tap % 3, q);
            if (HAS2) AH1 = lds_frag_w(pl, (hr1 + tap / 3) * 36 + hc1 + tap % 3, q);
        }
#pragma unroll
        for (int mg = 0; mg < 2; ++mg)
#pragma unroll
            for (int ng = 0; ng < 4; ++ng)
                gI[mg][ng] = __builtin_amdgcn_mfma_f32_16x16x32_f16(AI[mg], Bf[ng], gI[mg][ng], 0, 0, 0);
#pragma unroll
        for (int ng = 0; ng < 2; ++ng)
            gH[0][ng] = __builtin_amdgcn_mfma_f32_16x16x32_f16(AH0, Bf[ng], gH[0][ng], 0, 0, 0);
        if (HAS2) {
#pragma unroll
            for (int ng = 0; ng < 2; ++ng)
                gH[1][ng] = __builtin_amdgcn_mfma_f32_16x16x32_f16(AH1, Bf[ng], gH[1][ng], 0, 0, 0);
        }
    }

    // gates epilogue. C layout: col(n)=lane&15, row(pixel)=q*4+rg.
    // Interior: r*h -> rh LDS; z -> packed f16x2 REGISTERS (thread-aligned
    // with the update epilogue: same (q,m16,mg,rg) -> same (pixel, ch)).
    unsigned int zpk[2][4];
#pragma unroll
    for (int mg = 0; mg < 2; ++mg)
#pragma unroll
        for (int rg = 0; rg < 4; ++rg) {
            int gr = wv + 1, gc = mg * 16 + 1 + q * 4 + rg;
            zpk[mg][rg] = (unsigned int)f2h(sigmoid_f(gI[mg][2][rg]))
                        | ((unsigned int)f2h(sigmoid_f(gI[mg][3][rg])) << 16);
#pragma unroll
            for (int ng = 0; ng < 2; ++ng) {
                int n = ng * 16 + m16;
                float rv = sigmoid_f(gI[mg][ng][rg]);
                float hv = h2f(hp[((gr + 1) * 36 + gc + 1) * 32 + n]);
                rh[(gr * 34 + gc) * 32 + n] = f2h(rv * hv);
            }
        }
    // halo: r*h only
#pragma unroll
    for (int rg = 0; rg < 4; ++rg) {
        int gr, gc; halo_rc(wv * 16 + q * 4 + rg, gr, gc);
#pragma unroll
        for (int ng = 0; ng < 2; ++ng) {
            int n = ng * 16 + m16;
            float rv = sigmoid_f(gH[0][ng][rg]);
            float hv = h2f(hp[((gr + 1) * 36 + gc + 1) * 32 + n]);
            rh[(gr * 34 + gc) * 32 + n] = f2h(rv * hv);
        }
    }
    if (HAS2) {
#pragma unroll
        for (int rg = 0; rg < 4; ++rg) {
            int gr, gc; halo_rc(64 + q * 4 + rg, gr, gc);
#pragma unroll
            for (int ng = 0; ng < 2; ++ng) {
                int n = ng * 16 + m16;
                float rv = sigmoid_f(gH[1][ng][rg]);
                float hv = h2f(hp[((gr + 1) * 36 + gc + 1) * 32 + n]);
                rh[(gr * 34 + gc) * 32 + n] = f2h(rv * hv);
            }
        }
    }
    __syncthreads();

    // ---- phase 2: candidate conv on interior 4x32 (wave = 1 row, 2 m-tiles) ----
    f32x4 cacc[2][2];
#pragma unroll
    for (int mg = 0; mg < 2; ++mg)
#pragma unroll
        for (int ng = 0; ng < 2; ++ng) {
            float bv = bc[ng * 16 + m16];
            cacc[mg][ng] = f32x4{bv, bv, bv, bv};
        }
#pragma unroll
    for (int s = 0; s < KC; ++s) {
        f16x8 Bf[2];
#pragma unroll
        for (int ng = 0; ng < 2; ++ng)
            Bf[ng] = ld_frag(Wc + (s * 32 + ng * 16 + m16) * 32 + q * 8);
        f16x8 A2[2];
        if (L == 0 && s == 9) {
#pragma unroll
            for (int mg = 0; mg < 2; ++mg)
                A2[mg] = x_im2col(xt, wv + 1, mg * 16 + 1 + m16, q);
        } else if (L == 1 && s < 9) {
#pragma unroll
            for (int mg = 0; mg < 2; ++mg)
                A2[mg] = lds_frag_w(hs0, (wv + 1 + s / 3) * 36 + mg * 16 + m16 + 1 + s % 3, q);
        } else {
            const int tap = (L == 0) ? s : (s - 9);
#pragma unroll
            for (int mg = 0; mg < 2; ++mg)
                A2[mg] = lds_frag_w(rh, (wv + tap / 3) * 34 + mg * 16 + m16 + tap % 3, q);
        }
#pragma unroll
        for (int mg = 0; mg < 2; ++mg)
#pragma unroll
            for (int ng = 0; ng < 2; ++ng)
                cacc[mg][ng] = __builtin_amdgcn_mfma_f32_16x16x32_f16(A2[mg], Bf[ng], cacc[mg][ng], 0, 0, 0);
    }
    // update epilogue: h' = (1-z)*h_old + z*tanh(n); z from regs, h_old from LDS.
#pragma unroll
    for (int mg = 0; mg < 2; ++mg)
#pragma unroll
        for (int ng = 0; ng < 2; ++ng)
#pragma unroll
            for (int rg = 0; rg < 4; ++rg) {
                int lcol = mg * 16 + q * 4 + rg;
                int n = ng * 16 + m16;
                float nv = tanh_f(cacc[mg][ng][rg]);
                float zz = h2f((unsigned short)(zpk[mg][rg] >> (ng * 16)));
                float ho = h2f(hp[((wv + 2) * 36 + lcol + 2) * 32 + n]);
                long psp = (long)(b * PH + R0 + wv + 1) * PH + (C0 + lcol + 1);
                Hout[psp * 32 + n] = f2h((1.0f - zz) * ho + zz * nv);
            }
}

// ---- final: last h1 plane -> d_out NCHW fp32 ----
__global__ void final_out(const unsigned short* __restrict__ S1, float* __restrict__ out)
{
    int i = blockIdx.x * 256 + threadIdx.x;    // B*32*HW = 4194304
    if (i >= BB * 32 * HW) return;
    int pix = i & 16383;
    int t = i >> 14;
    int c = t & 31, b = t >> 5;
    int r = pix >> 7, cc = pix & 127;
    long ps = (long)(b * PH + r + 1) * PH + cc + 1;
    out[i] = h2f(S1[ps * 32 + c]);
}

extern "C" void kernel_launch(void* const* d_in, const int* in_sizes, int n_in,
                              void* d_out, int out_size, void* d_ws, size_t ws_size,
                              hipStream_t stream)
{
    const float* seq = (const float*)d_in[0];
    const float* gw0 = (const float*)d_in[1];
    const float* gb0 = (const float*)d_in[2];
    const float* cw0 = (const float*)d_in[3];
    const float* cb0 = (const float*)d_in[4];
    const float* gw1 = (const float*)d_in[5];
    const float* gb1 = (const float*)d_in[6];
    const float* cw1 = (const float*)d_in[7];
    const float* cb1 = (const float*)d_in[8];
    float* out = (float*)d_out;

    const size_t NSP = (size_t)BB * PH * PH * 32;    // 4,326,400 fp16 per plane

    char* p = (char*)d_ws;
    unsigned short* S0A = (unsigned short*)p; p += NSP * 2;
    unsigned short* S0B = (unsigned short*)p; p += NSP * 2;
    unsigned short* S1A = (unsigned short*)p; p += NSP * 2;
    unsigned short* S1B = (unsigned short*)p; p += NSP * 2;
    unsigned short* WG0 = (unsigned short*)p; p += 20480 * 2;
    unsigned short* WC0 = (unsigned short*)p; p += 10240 * 2;
    unsigned short* WG1 = (unsigned short*)p; p += 36864 * 2;
    unsigned short* WC1 = (unsigned short*)p; p += 18432 * 2;

    // zero all 4 state planes (h=0 init + permanent zero halos), one span
    hipMemsetAsync(S0A, 0, 4 * NSP * 2, stream);

    prep_w<<<(10 * 64 * 32 + 255) / 256, 256, 0, stream>>>(gw0, WG0, 64, 33, 10, 1);
    prep_w<<<(10 * 32 * 32 + 255) / 256, 256, 0, stream>>>(cw0, WC0, 32, 33, 10, 1);
    prep_w<<<(18 * 64 * 32 + 255) / 256, 256, 0, stream>>>(gw1, WG1, 64, 64, 18, 0);
    prep_w<<<(18 * 32 * 32 + 255) / 256, 256, 0, stream>>>(cw1, WC1, 32, 64, 18, 0);

    dim3 grid(128, BB), block(256);
    const long xbs = (long)TT * HW;
    unsigned short *s0r = S0A, *s0w = S0B, *s1r = S1A, *s1w = S1B;
    for (int t = 0; t < TT; ++t) {
        const float* xt = seq + (long)t * HW;
        cell_fused<0><<<grid, block, 0, stream>>>(s0r, s0w, (const unsigned short*)0,
                                                  xt, xbs, WG0, gb0, WC0, cb0);
        cell_fused<1><<<grid, block, 0, stream>>>(s1r, s1w, s0w,
                                                  (const float*)0, xbs, WG1, gb1, WC1, cb1);
        unsigned short* tmp;
        tmp = s0r; s0r = s0w; s0w = tmp;
        tmp = s1r; s1r = s1w; s1w = tmp;
    }
    final_out<<<(BB * 32 * HW + 255) / 256, 256, 0, stream>>>(s1r, out);
}